// Round 2
// baseline (383.351 us; speedup 1.0000x reference)
//
#include <hip/hip_runtime.h>
#include <hip/hip_bf16.h>

typedef unsigned short u16;
typedef unsigned int u32;
using floatx4 = __attribute__((ext_vector_type(4))) float;
using short8  = __attribute__((ext_vector_type(8))) short;
using bf16x8  = __attribute__((ext_vector_type(8))) __bf16;

#define B_ 4096
#define F_ 40
#define E_ 64
#define H_ 4
#define A_ 64
#define C_ 256

__device__ __forceinline__ float bf2f(u16 h) {
  u32 u = ((u32)h) << 16;
  return __builtin_bit_cast(float, u);
}
__device__ __forceinline__ u16 f2bf(float f) {  // RNE, finite inputs only
  u32 u = __builtin_bit_cast(u32, f);
  u32 r = (u + 0x7FFFu + ((u >> 16) & 1u)) >> 16;
  return (u16)r;
}
__device__ __forceinline__ floatx4 mfma16(bf16x8 a, bf16x8 b, floatx4 c) {
  return __builtin_amdgcn_mfma_f32_16x16x32_bf16(a, b, c, 0, 0, 0);
}

// dtype sniff: bf16 weights have sane exponents in all 64 u16s; fp32 data's
// low halves are random bits (expect ~40/64 sane). Threshold 56 (6.6 sigma).
__device__ __forceinline__ bool detect_bf16(const void* Wq) {
  int lane = threadIdx.x & 63;
  u16 w = ((const u16*)Wq)[lane];
  int e = (w >> 7) & 0xFF;
  bool sane = (e == 0) || (e >= 96 && e <= 159);
  return __popcll(__ballot(sane)) >= 56;
}

// element gather + hi/lo split straight from source weights (fallback path)
__device__ __forceinline__ void gather2(const void* W, bool bf, int stride, int col,
                                        int kc, int q, bf16x8& hi, bf16x8& lo) {
  short8 h8 = {0, 0, 0, 0, 0, 0, 0, 0}, l8 = {0, 0, 0, 0, 0, 0, 0, 0};
  int e0 = kc * 32 + q * 8;
#pragma unroll
  for (int j = 0; j < 8; ++j) {
    long off = (long)(e0 + j) * stride + col;
    float v = bf ? bf2f(((const u16*)W)[off]) : ((const float*)W)[off];
    u16 hh = f2bf(v);
    h8[j] = (short)hh;
    l8[j] = (short)f2bf(v - bf2f(hh));
  }
  hi = __builtin_bit_cast(bf16x8, h8);
  lo = __builtin_bit_cast(bf16x8, l8);
}

// Pack weights into MFMA B-fragment order, hi and lo parts.
// ws u16 layout: [WqH 16384][WkH][WvH][WresH][WqL][WkL]  (6*16384 = 98304)
// frag(h,t,kc) elem[lane*8+j] = W[h][e=kc*32+(lane>>4)*8+j][t*16+(lane&15)]
__global__ void pack_w(const void* __restrict__ Wq, const void* __restrict__ Wk,
                       const void* __restrict__ Wv, const void* __restrict__ Wres,
                       u16* __restrict__ ws) {
  bool bf = detect_bf16(Wq);
  int idx = blockIdx.x * 256 + threadIdx.x;  // 0..98303
  int s = idx >> 14;
  int within = idx & 16383;
  int frag = within >> 9;
  int h = frag >> 3, t = (frag >> 1) & 3, kc = frag & 1;
  int pos = within & 511;
  int lane = pos >> 3, j = pos & 7;
  int q = lane >> 4, r = lane & 15;
  int e = kc * 32 + q * 8 + j;
  bool lo = (s >= 4);
  int sm = lo ? (s - 4) : s;
  const void* src;
  long off;
  if (sm == 0)      { src = Wq;   off = (long)(h * 64 + e) * 64 + t * 16 + r; }
  else if (sm == 1) { src = Wk;   off = (long)(h * 64 + e) * 64 + t * 16 + r; }
  else if (sm == 2) { src = Wv;   off = (long)(h * 64 + e) * 64 + t * 16 + r; }
  else              { src = Wres; off = (long)e * 256 + h * 64 + t * 16 + r; }
  float v = bf ? bf2f(((const u16*)src)[off]) : ((const float*)src)[off];
  u16 hi = f2bf(v);
  ws[idx] = lo ? f2bf(v - bf2f(hi)) : hi;
}

// One block = one (batch b, head h). 4 waves.
// Phase 1: wave w projects Q,K column-tile nt=w (split bf16) and V^T a-tile w.
// Phase 2a: waves 0-2 own f-row-tile mt=w: S (split), softmax, P. Wave 3: residual -> R (fp32).
// Phase 2b: waves 0-2: O = P.V + R, relu, store.
template <bool USEWS>
__global__ __launch_bounds__(256, 2) void autoint_attn(
    const void* __restrict__ Xv, const void* __restrict__ Wq,
    const void* __restrict__ Wk, const void* __restrict__ Wv,
    const void* __restrict__ Wres, const u16* __restrict__ wp,
    void* __restrict__ outv) {
  __shared__ __align__(16) u16 smem[30816];  // 61632 B
  const int tid = threadIdx.x;
  const int b = blockIdx.x >> 2;
  const int h = blockIdx.x & 3;
  const int w = tid >> 6, lane = tid & 63;
  const int q = lane >> 4, r = lane & 15;
  const bool bf = detect_bf16(Wq);

  u16* XH = smem;                     // [3 mt][2 kc][64 lane][8]  3072
  u16* XL = smem + 3072;              // 3072
  u16* QH = smem + 6144;              // [48][72]  3456 (aliased by P later)
  u16* QL = smem + 9600;              // 3456
  u16* KH = smem + 13056;             // 3456
  u16* KL = smem + 16512;             // 3456
  u16* VT = smem + 19968;             // [64][72]  4608
  float* R = (float*)(smem + 24576);  // [48][65] fp32 residual

  // ---- stage X into split A-frag layout (pad rows 40..47 = 0) ----
  for (int c = tid; c < 384; c += 256) {
    short8 hi8 = {0, 0, 0, 0, 0, 0, 0, 0}, lo8 = {0, 0, 0, 0, 0, 0, 0, 0};
    int f, ec;
    if (c < 320) {
      f = c >> 3; ec = c & 7;
      if (bf) {
        hi8 = *(const short8*)((const u16*)Xv + ((size_t)b * F_ + f) * E_ + ec * 8);
      } else {
        const float* xp = (const float*)Xv + ((size_t)b * F_ + f) * E_ + ec * 8;
        float4 p0 = *(const float4*)xp;
        float4 p1 = *(const float4*)(xp + 4);
        float vals[8] = {p0.x, p0.y, p0.z, p0.w, p1.x, p1.y, p1.z, p1.w};
#pragma unroll
        for (int j = 0; j < 8; ++j) {
          u16 hh = f2bf(vals[j]);
          hi8[j] = (short)hh;
          lo8[j] = (short)f2bf(vals[j] - bf2f(hh));
        }
      }
    } else {
      f = 40 + ((c - 320) >> 3); ec = c & 7;
    }
    int mt = f >> 4, rr = f & 15, kc = ec >> 2, qq = ec & 3;
    int base = ((mt * 2 + kc) * 64 + qq * 16 + rr) * 8;
    *(short8*)(XH + base) = hi8;
    *(short8*)(XL + base) = lo8;
  }
  __syncthreads();

  bf16x8 xh[3][2], xl[3][2];
#pragma unroll
  for (int mt = 0; mt < 3; ++mt)
#pragma unroll
    for (int kc = 0; kc < 2; ++kc) {
      xh[mt][kc] = *(const bf16x8*)(XH + ((mt * 2 + kc) * 64 + lane) * 8);
      xl[mt][kc] = *(const bf16x8*)(XL + ((mt * 2 + kc) * 64 + lane) * 8);
    }

  const u16* PQH = wp;
  const u16* PKH = wp + 16384;
  const u16* PVH = wp + 32768;
  const u16* PRH = wp + 49152;
  const u16* PQL = wp + 65536;
  const u16* PKL = wp + 81920;
  const void* Wq_p = bf ? (const void*)((const u16*)Wq + h * 4096)
                        : (const void*)((const float*)Wq + h * 4096);
  const void* Wk_p = bf ? (const void*)((const u16*)Wk + h * 4096)
                        : (const void*)((const float*)Wk + h * 4096);
  const void* Wv_p = bf ? (const void*)((const u16*)Wv + h * 4096)
                        : (const void*)((const float*)Wv + h * 4096);

  // ---- Phase 1: Q,K split projection, column tile nt = w ----
  {
    const int nt = w;
    bf16x8 qhf[2], qlf[2], khf[2], klf[2];
    if constexpr (USEWS) {
#pragma unroll
      for (int kc = 0; kc < 2; ++kc) {
        qhf[kc] = *(const bf16x8*)(PQH + ((h * 4 + nt) * 2 + kc) * 512 + lane * 8);
        qlf[kc] = *(const bf16x8*)(PQL + ((h * 4 + nt) * 2 + kc) * 512 + lane * 8);
        khf[kc] = *(const bf16x8*)(PKH + ((h * 4 + nt) * 2 + kc) * 512 + lane * 8);
        klf[kc] = *(const bf16x8*)(PKL + ((h * 4 + nt) * 2 + kc) * 512 + lane * 8);
      }
    } else {
      for (int kc = 0; kc < 2; ++kc) {
        gather2(Wq_p, bf, 64, nt * 16 + r, kc, q, qhf[kc], qlf[kc]);
        gather2(Wk_p, bf, 64, nt * 16 + r, kc, q, khf[kc], klf[kc]);
      }
    }
#pragma unroll
    for (int mt = 0; mt < 3; ++mt) {
      floatx4 aq = {0.f, 0.f, 0.f, 0.f}, ak = {0.f, 0.f, 0.f, 0.f};
#pragma unroll
      for (int kc = 0; kc < 2; ++kc) {
        aq = mfma16(xh[mt][kc], qhf[kc], aq);
        aq = mfma16(xh[mt][kc], qlf[kc], aq);
        aq = mfma16(xl[mt][kc], qhf[kc], aq);
        ak = mfma16(xh[mt][kc], khf[kc], ak);
        ak = mfma16(xh[mt][kc], klf[kc], ak);
        ak = mfma16(xl[mt][kc], khf[kc], ak);
      }
#pragma unroll
      for (int i = 0; i < 4; ++i) {
        int row = mt * 16 + q * 4 + i, col = nt * 16 + r;
        float qv = aq[i];
        u16 qh16 = f2bf(qv);
        QH[row * 72 + col] = qh16;
        QL[row * 72 + col] = f2bf(qv - bf2f(qh16));
        float kv = ak[i];
        u16 kh16 = f2bf(kv);
        KH[row * 72 + col] = kh16;
        KL[row * 72 + col] = f2bf(kv - bf2f(kh16));
      }
    }
  }

  // ---- Phase 1: V^T = Wv^T . X^T, a-row-tile w ----
  {
    const int mta = w;
    bf16x8 wv[2], dmy;
    if constexpr (USEWS) {
#pragma unroll
      for (int kc = 0; kc < 2; ++kc)
        wv[kc] = *(const bf16x8*)(PVH + ((h * 4 + mta) * 2 + kc) * 512 + lane * 8);
    } else {
      for (int kc = 0; kc < 2; ++kc)
        gather2(Wv_p, bf, 64, mta * 16 + r, kc, q, wv[kc], dmy);
    }
#pragma unroll
    for (int nt = 0; nt < 3; ++nt) {
      floatx4 acc = {0.f, 0.f, 0.f, 0.f};
      acc = mfma16(wv[0], xh[nt][0], acc);
      acc = mfma16(wv[1], xh[nt][1], acc);
#pragma unroll
      for (int i = 0; i < 4; ++i)
        VT[(mta * 16 + q * 4 + i) * 72 + nt * 16 + r] = f2bf(acc[i]);
    }
    if (lane < 32) {  // zero K-dim pad cols g=48..63
      short8 z = {0, 0, 0, 0, 0, 0, 0, 0};
      *(short8*)(VT + (mta * 16 + (lane >> 1)) * 72 + 48 + (lane & 1) * 8) = z;
    }
  }
  __syncthreads();

  // ---- Phase 2a ----
  bf16x8 pf[2];
  if (w < 3) {
    const int mt = w;
    bf16x8 qhf2[2], qlf2[2];
#pragma unroll
    for (int kc = 0; kc < 2; ++kc) {
      qhf2[kc] = *(const bf16x8*)(QH + (mt * 16 + r) * 72 + kc * 32 + q * 8);
      qlf2[kc] = *(const bf16x8*)(QL + (mt * 16 + r) * 72 + kc * 32 + q * 8);
    }
    floatx4 sg[3];
#pragma unroll
    for (int gt = 0; gt < 3; ++gt) {
      floatx4 s = {0.f, 0.f, 0.f, 0.f};
#pragma unroll
      for (int kc = 0; kc < 2; ++kc) {
        bf16x8 kh = *(const bf16x8*)(KH + (gt * 16 + r) * 72 + kc * 32 + q * 8);
        bf16x8 kl = *(const bf16x8*)(KL + (gt * 16 + r) * 72 + kc * 32 + q * 8);
        s = mfma16(qhf2[kc], kh, s);
        s = mfma16(qhf2[kc], kl, s);
        s = mfma16(qlf2[kc], kh, s);
      }
      sg[gt] = s;
    }
    const bool ok2 = (r < 8);  // col 32+r valid iff < 40
#pragma unroll
    for (int i = 0; i < 4; ++i) {
      float v0 = sg[0][i], v1 = sg[1][i], v2 = sg[2][i];
      float m = fmaxf(v0, v1);
      if (ok2) m = fmaxf(m, v2);
#pragma unroll
      for (int d = 1; d < 16; d <<= 1) m = fmaxf(m, __shfl_xor(m, d, 64));
      float p0 = __expf(v0 - m);
      float p1 = __expf(v1 - m);
      float p2 = ok2 ? __expf(v2 - m) : 0.f;
      float sum = p0 + p1 + p2;
#pragma unroll
      for (int d = 1; d < 16; d <<= 1) sum += __shfl_xor(sum, d, 64);
      float inv = 1.f / sum;
      int row = mt * 16 + q * 4 + i;
      QH[row * 72 + r]      = f2bf(p0 * inv);   // P aliases QH (own rows only)
      QH[row * 72 + 16 + r] = f2bf(p1 * inv);
      QH[row * 72 + 32 + r] = f2bf(p2 * inv);
      QH[row * 72 + 48 + r] = 0;                // K-dim pad
    }
    pf[0] = *(const bf16x8*)(QH + (mt * 16 + r) * 72 + q * 8);
    pf[1] = *(const bf16x8*)(QH + (mt * 16 + r) * 72 + 32 + q * 8);
  } else {
    // wave 3: residual X.Wres -> R fp32
    for (int nt = 0; nt < 4; ++nt) {
      bf16x8 wr[2], dmy;
      if constexpr (USEWS) {
#pragma unroll
        for (int kc = 0; kc < 2; ++kc)
          wr[kc] = *(const bf16x8*)(PRH + ((h * 4 + nt) * 2 + kc) * 512 + lane * 8);
      } else {
        for (int kc = 0; kc < 2; ++kc)
          gather2(Wres, bf, 256, h * 64 + nt * 16 + r, kc, q, wr[kc], dmy);
      }
#pragma unroll
      for (int mt2 = 0; mt2 < 3; ++mt2) {
        floatx4 acc = {0.f, 0.f, 0.f, 0.f};
        acc = mfma16(xh[mt2][0], wr[0], acc);
        acc = mfma16(xh[mt2][1], wr[1], acc);
#pragma unroll
        for (int i = 0; i < 4; ++i)
          R[(mt2 * 16 + q * 4 + i) * 65 + nt * 16 + r] = acc[i];
      }
    }
  }
  __syncthreads();

  // ---- Phase 2b: O = P.V + R, relu, store ----
  if (w < 3) {
    const int mt = w;
#pragma unroll
    for (int nt = 0; nt < 4; ++nt) {
      floatx4 acc;
#pragma unroll
      for (int i = 0; i < 4; ++i) acc[i] = R[(mt * 16 + q * 4 + i) * 65 + nt * 16 + r];
      bf16x8 vb0 = *(const bf16x8*)(VT + (nt * 16 + r) * 72 + q * 8);
      bf16x8 vb1 = *(const bf16x8*)(VT + (nt * 16 + r) * 72 + 32 + q * 8);
      acc = mfma16(pf[0], vb0, acc);
      acc = mfma16(pf[1], vb1, acc);
#pragma unroll
      for (int i = 0; i < 4; ++i) {
        int f = mt * 16 + q * 4 + i;
        if (f < F_) {
          size_t o = ((size_t)b * F_ + f) * C_ + h * 64 + nt * 16 + r;
          float val = fmaxf(acc[i], 0.f);
          if (bf) ((u16*)outv)[o] = f2bf(val);
          else    ((float*)outv)[o] = val;
        }
      }
    }
  }
}

extern "C" void kernel_launch(void* const* d_in, const int* in_sizes, int n_in,
                              void* d_out, int out_size, void* d_ws, size_t ws_size,
                              hipStream_t stream) {
  (void)in_sizes; (void)n_in; (void)out_size;
  const void* X    = d_in[0];
  const void* Wq   = d_in[1];
  const void* Wk   = d_in[2];
  const void* Wv   = d_in[3];
  const void* Wres = d_in[4];

  bool usews = (d_ws != nullptr) && (ws_size >= 196608);
  if (usews) {
    pack_w<<<384, 256, 0, stream>>>(Wq, Wk, Wv, Wres, (u16*)d_ws);
    autoint_attn<true><<<B_ * H_, 256, 0, stream>>>(X, Wq, Wk, Wv, Wres,
                                                    (const u16*)d_ws, d_out);
  } else {
    autoint_attn<false><<<B_ * H_, 256, 0, stream>>>(X, Wq, Wk, Wv, Wres,
                                                     nullptr, d_out);
  }
}